// Round 8
// baseline (200.232 us; speedup 1.0000x reference)
//
#include <hip/hip_runtime.h>
#include <math.h>

#define BTILE 1024

// Equal-work chamfer blocks. 256 threads; SLOTS = 1<<LOG_SLOTS A-slots,
// NSEG = 256/SLOTS B-segments, 2 A-points per thread (slot, slot+SLOTS).
// Every instantiation does (Bn/BTILE) * (BTILE/NSEG) / 4 = 32 g-iterations
// per thread when Bn*... shapes are chosen so Bn/NSEG = 128.
// min_b |a-b|^2 = a2 + min_b(b2 - 2 a.b); LDS planes {-2bx,-2by,-2bz,b2}.
template<int LOG_SLOTS, bool A_PLANAR, bool B_PLANAR>
__device__ __forceinline__ float chamfer_block(
    const float* __restrict__ A, int An,
    const float* __restrict__ B, int Bn,
    int lbid, float scale,
    float (&sb)[4][BTILE], float (&red)[512])
{
    constexpr int SLOTS = 1 << LOG_SLOTS;
    constexpr int NSEG  = 256 >> LOG_SLOTS;
    constexpr int SEG   = BTILE / NSEG;     // B-points per thread per tile

    const int bpb   = An / (2 * SLOTS);     // blocks per batch
    const int batch = lbid / bpb;
    const int ablk  = lbid % bpb;
    const float* __restrict__ Ab = A + (size_t)batch * 3 * An;
    const float* __restrict__ Bb = B + (size_t)batch * 3 * Bn;

    const int tid  = threadIdx.x;
    const int slot = tid & (SLOTS - 1);
    const int sp   = tid >> LOG_SLOTS;
    const int p0   = ablk * (2 * SLOTS) + slot;
    const int p1   = p0 + SLOTS;

    float a0x, a0y, a0z, a1x, a1y, a1z;
    if (A_PLANAR) {
        a0x = Ab[p0];   a0y = Ab[An + p0];  a0z = Ab[2*An + p0];
        a1x = Ab[p1];   a1y = Ab[An + p1];  a1z = Ab[2*An + p1];
    } else {
        a0x = Ab[3*p0]; a0y = Ab[3*p0 + 1]; a0z = Ab[3*p0 + 2];
        a1x = Ab[3*p1]; a1y = Ab[3*p1 + 1]; a1z = Ab[3*p1 + 2];
    }
    const float a0s = fmaf(a0x, a0x, fmaf(a0y, a0y, a0z * a0z));
    const float a1s = fmaf(a1x, a1x, fmaf(a1y, a1y, a1z * a1z));

    const float BIG = 3.402823466e38f;
    float n00 = BIG, n01 = BIG, n10 = BIG, n11 = BIG;

    const int NT = Bn / BTILE;
    for (int t = 0; t < NT; ++t) {
        const int t0 = t * BTILE;
        // ---- stage pre-scaled tile (4 fully-unrolled rounds) ----
#pragma unroll
        for (int i = 0; i < 4; ++i) {
            const int k = tid + i * 256;
            float x, y, z;
            if (B_PLANAR) {
                x = Bb[t0 + k]; y = Bb[Bn + t0 + k]; z = Bb[2*Bn + t0 + k];
            } else {
                int base = 3 * (t0 + k);
                x = Bb[base]; y = Bb[base + 1]; z = Bb[base + 2];
            }
            sb[0][k] = -2.0f * x;
            sb[1][k] = -2.0f * y;
            sb[2][k] = -2.0f * z;
            sb[3][k] = fmaf(x, x, fmaf(y, y, z * z));
        }
        __syncthreads();

        const float4* __restrict__ px = (const float4*)&sb[0][sp * SEG];
        const float4* __restrict__ py = (const float4*)&sb[1][sp * SEG];
        const float4* __restrict__ pz = (const float4*)&sb[2][sp * SEG];
        const float4* __restrict__ pw = (const float4*)&sb[3][sp * SEG];
#pragma unroll 2
        for (int g = 0; g < SEG / 4; ++g) {
            float4 x = px[g], y = py[g], z = pz[g], w = pw[g];
            float d0, d1, d2, d3;
            d0 = fmaf(a0x, x.x, fmaf(a0y, y.x, fmaf(a0z, z.x, w.x)));
            d1 = fmaf(a0x, x.y, fmaf(a0y, y.y, fmaf(a0z, z.y, w.y)));
            d2 = fmaf(a0x, x.z, fmaf(a0y, y.z, fmaf(a0z, z.z, w.z)));
            d3 = fmaf(a0x, x.w, fmaf(a0y, y.w, fmaf(a0z, z.w, w.w)));
            n00 = fminf(fminf(d0, d1), n00);       // v_min3_f32
            n01 = fminf(fminf(d2, d3), n01);
            d0 = fmaf(a1x, x.x, fmaf(a1y, y.x, fmaf(a1z, z.x, w.x)));
            d1 = fmaf(a1x, x.y, fmaf(a1y, y.y, fmaf(a1z, z.y, w.y)));
            d2 = fmaf(a1x, x.z, fmaf(a1y, y.z, fmaf(a1z, z.z, w.z)));
            d3 = fmaf(a1x, x.w, fmaf(a1y, y.w, fmaf(a1z, z.w, w.w)));
            n10 = fminf(fminf(d0, d1), n10);
            n11 = fminf(fminf(d2, d3), n11);
        }
        __syncthreads();
    }

    // ---- min across NSEG segments, per A-slot ----
    red[sp * SLOTS + slot]       = fminf(n00, n01);
    red[256 + sp * SLOTS + slot] = fminf(n10, n11);
    __syncthreads();
#pragma unroll
    for (int st = NSEG / 2; st > 0; st >>= 1) {
        if (sp < st) {
            red[sp*SLOTS + slot] =
                fminf(red[sp*SLOTS + slot], red[(sp+st)*SLOTS + slot]);
            red[256 + sp*SLOTS + slot] =
                fminf(red[256 + sp*SLOTS + slot], red[256 + (sp+st)*SLOTS + slot]);
        }
        __syncthreads();
    }

    float contrib = 0.0f;
    if (tid < SLOTS) {
        float d = fmaxf(0.0f, a0s + red[slot]) + fmaxf(0.0f, a1s + red[256 + slot]);
        d *= scale;
#pragma unroll
        for (int off = SLOTS / 2; off > 0; off >>= 1) d += __shfl_down(d, off, SLOTS);
        contrib = d;   // valid at tid 0
    }
    return contrib;
}

__device__ __forceinline__ float kp_block(const float* __restrict__ a,
                                          const float* __restrict__ b, int n,
                                          float (&red)[512])
{
    int tid = threadIdx.x;
    float s = 0.0f;
    for (int i = tid; i < n; i += 256) {
        float d = a[i] - b[i];
        s = fmaf(d, d, s);
    }
    for (int off = 32; off > 0; off >>= 1) s += __shfl_down(s, off, 64);
    if ((tid & 63) == 0) red[tid >> 6] = s;
    __syncthreads();
    float r = 0.0f;
    if (tid == 0) r = (red[0] + red[1] + red[2] + red[3]) / (float)n;
    return r;
}

// ws: [0..3] float acc, [16..19] uint done-counter. memset(0,64) first.
__global__ __launch_bounds__(256, 8) void fused_all(
    const float* __restrict__ pred, const float* __restrict__ target, int nkp,
    const float* __restrict__ coarse, int Nc,
    const float* __restrict__ fine, int Nf,
    const float* __restrict__ gt, int M,
    int r1, int r2, int r3, int r4,
    float sc_f1, float sc_f2, float sc_c1, float sc_c2,
    float* __restrict__ ws, float* __restrict__ out)
{
    __shared__ __align__(16) float sb[4][BTILE];
    __shared__ float red[512];
    const int bid = blockIdx.x;
    const int nb  = gridDim.x;

    float contrib;
    if (bid < r1)        // fine vs gt: 16 A-pts, 32-way split, 4 tiles
        contrib = chamfer_block<3, true,  false>(fine,   Nf, gt,     M,  bid,      sc_f1, sb, red);
    else if (bid < r2)   // gt vs fine: 16 A-pts, 32-way split, 4 tiles
        contrib = chamfer_block<3, false, true >(gt,     M,  fine,   Nf, bid - r1, sc_f2, sb, red);
    else if (bid < r3)   // coarse vs gt: 16 A-pts, 32-way split, 4 tiles
        contrib = chamfer_block<3, true,  false>(coarse, Nc, gt,     M,  bid - r2, sc_c1, sb, red);
    else if (bid < r4)   // gt vs coarse: 64 A-pts, 8-way split, 1 tile (equal work)
        contrib = chamfer_block<5, false, true >(gt,     M,  coarse, Nc, bid - r3, sc_c2, sb, red);
    else
        contrib = kp_block(pred, target, nkp, red);

    if (threadIdx.x == 0) {
        atomicAdd(ws, contrib);
        __threadfence();
        unsigned old = atomicAdd((unsigned*)ws + 4, 1u);
        if (old == (unsigned)(nb - 1)) {
            __threadfence();
            out[0] = atomicAdd(ws, 0.0f);
        }
    }
}

extern "C" void kernel_launch(void* const* d_in, const int* in_sizes, int n_in,
                              void* d_out, int out_size, void* d_ws, size_t ws_size,
                              hipStream_t stream) {
    const float* pred   = (const float*)d_in[0];
    const float* target = (const float*)d_in[1];
    const float* coarse = (const float*)d_in[2]; // [B,3,Nc]
    const float* fine   = (const float*)d_in[3]; // [B,3,Nf]
    const float* gt     = (const float*)d_in[4]; // [B,M,3]
    float* out = (float*)d_out;
    float* ws  = (float*)d_ws;

    const int nkp = in_sizes[0];            // 240
    const int B   = nkp / 30;               // 8
    const int Nc  = in_sizes[2] / (3 * B);  // 1024
    const int Nf  = in_sizes[3] / (3 * B);  // 4096
    const int M   = in_sizes[4] / (3 * B);  // 4096

    const int nb_f1 = B * (Nf / 16);        // 2048
    const int nb_f2 = B * (M  / 16);        // 2048
    const int nb_c1 = B * (Nc / 16);        // 512
    const int r1 = nb_f1;
    const int r2 = r1 + nb_f2;
    const int r3 = r2 + nb_c1;
    const int r4 = r3 + B * (M / 64);       // c2: 64 A-points per block -> 512 blocks
    const int nb = r4 + 1;                  // + kp -> 5121

    hipMemsetAsync(ws, 0, 64, stream);
    fused_all<<<nb, 256, 0, stream>>>(
        pred, target, nkp, coarse, Nc, fine, Nf, gt, M,
        r1, r2, r3, r4,
        1.0f / (B * Nf), 1.0f / (B * M), 1.0f / (B * Nc), 1.0f / (B * M),
        ws, out);
}

// Round 9
// 198.850 us; speedup vs baseline: 1.0069x; 1.0069x over previous
//
#include <hip/hip_runtime.h>
#include <math.h>

#define BTILE 1024

// Equal-work chamfer blocks, bank-conflict-free LDS layout.
// 256 threads; SLOTS = 1<<LOG_SLOTS A-slots, NSEG = 256/SLOTS B-segments,
// 2 A-points per thread (slot, slot+SLOTS). Segments are PADDED to SEGP =
// SEG+4 floats so the per-wave sp-groups (byte stride SEGP*4) spread across
// bank quads: bank = (sp*SEGP + g*4) % 32 = 4*sp + 4*g  -> conflict-free.
// (Round-8 unpadded SEG=32 layout was an 8-way conflict: 9.4M conflict cyc.)
// min_b |a-b|^2 = a2 + min_b(b2 - 2 a.b); LDS planes {-2bx,-2by,-2bz,b2}.
#define SBROW 1152   // max NSEG*SEGP = 32*36 (LOG_SLOTS=3); LOG_SLOTS=5: 8*132=1056

template<int LOG_SLOTS, bool A_PLANAR, bool B_PLANAR>
__device__ __forceinline__ float chamfer_block(
    const float* __restrict__ A, int An,
    const float* __restrict__ B, int Bn,
    int lbid, float scale,
    float (&sb)[4][SBROW], float (&red)[512])
{
    constexpr int SLOTS   = 1 << LOG_SLOTS;
    constexpr int NSEG    = 256 >> LOG_SLOTS;
    constexpr int LOG_SEG = LOG_SLOTS + 2;      // SEG = BTILE/NSEG = 2^(LOG_SLOTS+2)
    constexpr int SEG     = 1 << LOG_SEG;
    constexpr int SEGP    = SEG + 4;            // padded segment stride (floats)

    const int bpb   = An / (2 * SLOTS);         // blocks per batch
    const int batch = lbid / bpb;
    const int ablk  = lbid % bpb;
    const float* __restrict__ Ab = A + (size_t)batch * 3 * An;
    const float* __restrict__ Bb = B + (size_t)batch * 3 * Bn;

    const int tid  = threadIdx.x;
    const int slot = tid & (SLOTS - 1);
    const int sp   = tid >> LOG_SLOTS;
    const int p0   = ablk * (2 * SLOTS) + slot;
    const int p1   = p0 + SLOTS;

    float a0x, a0y, a0z, a1x, a1y, a1z;
    if (A_PLANAR) {
        a0x = Ab[p0];   a0y = Ab[An + p0];  a0z = Ab[2*An + p0];
        a1x = Ab[p1];   a1y = Ab[An + p1];  a1z = Ab[2*An + p1];
    } else {
        a0x = Ab[3*p0]; a0y = Ab[3*p0 + 1]; a0z = Ab[3*p0 + 2];
        a1x = Ab[3*p1]; a1y = Ab[3*p1 + 1]; a1z = Ab[3*p1 + 2];
    }
    const float a0s = fmaf(a0x, a0x, fmaf(a0y, a0y, a0z * a0z));
    const float a1s = fmaf(a1x, a1x, fmaf(a1y, a1y, a1z * a1z));

    const float BIG = 3.402823466e38f;
    float n00 = BIG, n01 = BIG, n10 = BIG, n11 = BIG;

    const int NT = Bn / BTILE;
    for (int t = 0; t < NT; ++t) {
        const int t0 = t * BTILE;
        // ---- stage pre-scaled tile into padded layout ----
#pragma unroll
        for (int i = 0; i < 4; ++i) {
            const int k = tid + i * 256;
            float x, y, z;
            if (B_PLANAR) {
                x = Bb[t0 + k]; y = Bb[Bn + t0 + k]; z = Bb[2*Bn + t0 + k];
            } else {
                int base = 3 * (t0 + k);
                x = Bb[base]; y = Bb[base + 1]; z = Bb[base + 2];
            }
            const int addr = (k >> LOG_SEG) * SEGP + (k & (SEG - 1));
            sb[0][addr] = -2.0f * x;
            sb[1][addr] = -2.0f * y;
            sb[2][addr] = -2.0f * z;
            sb[3][addr] = fmaf(x, x, fmaf(y, y, z * z));
        }
        __syncthreads();

        const float4* __restrict__ px = (const float4*)&sb[0][sp * SEGP];
        const float4* __restrict__ py = (const float4*)&sb[1][sp * SEGP];
        const float4* __restrict__ pz = (const float4*)&sb[2][sp * SEGP];
        const float4* __restrict__ pw = (const float4*)&sb[3][sp * SEGP];
#pragma unroll 2
        for (int g = 0; g < SEG / 4; ++g) {
            float4 x = px[g], y = py[g], z = pz[g], w = pw[g];
            float d0, d1, d2, d3;
            d0 = fmaf(a0x, x.x, fmaf(a0y, y.x, fmaf(a0z, z.x, w.x)));
            d1 = fmaf(a0x, x.y, fmaf(a0y, y.y, fmaf(a0z, z.y, w.y)));
            d2 = fmaf(a0x, x.z, fmaf(a0y, y.z, fmaf(a0z, z.z, w.z)));
            d3 = fmaf(a0x, x.w, fmaf(a0y, y.w, fmaf(a0z, z.w, w.w)));
            n00 = fminf(fminf(d0, d1), n00);       // v_min3_f32
            n01 = fminf(fminf(d2, d3), n01);
            d0 = fmaf(a1x, x.x, fmaf(a1y, y.x, fmaf(a1z, z.x, w.x)));
            d1 = fmaf(a1x, x.y, fmaf(a1y, y.y, fmaf(a1z, z.y, w.y)));
            d2 = fmaf(a1x, x.z, fmaf(a1y, y.z, fmaf(a1z, z.z, w.z)));
            d3 = fmaf(a1x, x.w, fmaf(a1y, y.w, fmaf(a1z, z.w, w.w)));
            n10 = fminf(fminf(d0, d1), n10);
            n11 = fminf(fminf(d2, d3), n11);
        }
        __syncthreads();
    }

    // ---- min across NSEG segments, per A-slot ----
    red[sp * SLOTS + slot]       = fminf(n00, n01);
    red[256 + sp * SLOTS + slot] = fminf(n10, n11);
    __syncthreads();
#pragma unroll
    for (int st = NSEG / 2; st > 0; st >>= 1) {
        if (sp < st) {
            red[sp*SLOTS + slot] =
                fminf(red[sp*SLOTS + slot], red[(sp+st)*SLOTS + slot]);
            red[256 + sp*SLOTS + slot] =
                fminf(red[256 + sp*SLOTS + slot], red[256 + (sp+st)*SLOTS + slot]);
        }
        __syncthreads();
    }

    float contrib = 0.0f;
    if (tid < SLOTS) {
        float d = fmaxf(0.0f, a0s + red[slot]) + fmaxf(0.0f, a1s + red[256 + slot]);
        d *= scale;
#pragma unroll
        for (int off = SLOTS / 2; off > 0; off >>= 1) d += __shfl_down(d, off, SLOTS);
        contrib = d;   // valid at tid 0
    }
    return contrib;
}

__device__ __forceinline__ float kp_block(const float* __restrict__ a,
                                          const float* __restrict__ b, int n,
                                          float (&red)[512])
{
    int tid = threadIdx.x;
    float s = 0.0f;
    for (int i = tid; i < n; i += 256) {
        float d = a[i] - b[i];
        s = fmaf(d, d, s);
    }
    for (int off = 32; off > 0; off >>= 1) s += __shfl_down(s, off, 64);
    if ((tid & 63) == 0) red[tid >> 6] = s;
    __syncthreads();
    float r = 0.0f;
    if (tid == 0) r = (red[0] + red[1] + red[2] + red[3]) / (float)n;
    return r;
}

// ws: [0..3] float acc, [16..19] uint done-counter. memset(0,64) first.
__global__ __launch_bounds__(256, 8) void fused_all(
    const float* __restrict__ pred, const float* __restrict__ target, int nkp,
    const float* __restrict__ coarse, int Nc,
    const float* __restrict__ fine, int Nf,
    const float* __restrict__ gt, int M,
    int r1, int r2, int r3, int r4,
    float sc_f1, float sc_f2, float sc_c1, float sc_c2,
    float* __restrict__ ws, float* __restrict__ out)
{
    __shared__ __align__(16) float sb[4][SBROW];
    __shared__ float red[512];
    const int bid = blockIdx.x;
    const int nb  = gridDim.x;

    float contrib;
    if (bid < r1)        // fine vs gt: 16 A-pts, 32-way split, 4 tiles
        contrib = chamfer_block<3, true,  false>(fine,   Nf, gt,     M,  bid,      sc_f1, sb, red);
    else if (bid < r2)   // gt vs fine: 16 A-pts, 32-way split, 4 tiles
        contrib = chamfer_block<3, false, true >(gt,     M,  fine,   Nf, bid - r1, sc_f2, sb, red);
    else if (bid < r3)   // coarse vs gt: 16 A-pts, 32-way split, 4 tiles
        contrib = chamfer_block<3, true,  false>(coarse, Nc, gt,     M,  bid - r2, sc_c1, sb, red);
    else if (bid < r4)   // gt vs coarse: 64 A-pts, 8-way split, 1 tile (equal work)
        contrib = chamfer_block<5, false, true >(gt,     M,  coarse, Nc, bid - r3, sc_c2, sb, red);
    else
        contrib = kp_block(pred, target, nkp, red);

    if (threadIdx.x == 0) {
        atomicAdd(ws, contrib);
        __threadfence();
        unsigned old = atomicAdd((unsigned*)ws + 4, 1u);
        if (old == (unsigned)(nb - 1)) {
            __threadfence();
            out[0] = atomicAdd(ws, 0.0f);
        }
    }
}

extern "C" void kernel_launch(void* const* d_in, const int* in_sizes, int n_in,
                              void* d_out, int out_size, void* d_ws, size_t ws_size,
                              hipStream_t stream) {
    const float* pred   = (const float*)d_in[0];
    const float* target = (const float*)d_in[1];
    const float* coarse = (const float*)d_in[2]; // [B,3,Nc]
    const float* fine   = (const float*)d_in[3]; // [B,3,Nf]
    const float* gt     = (const float*)d_in[4]; // [B,M,3]
    float* out = (float*)d_out;
    float* ws  = (float*)d_ws;

    const int nkp = in_sizes[0];            // 240
    const int B   = nkp / 30;               // 8
    const int Nc  = in_sizes[2] / (3 * B);  // 1024
    const int Nf  = in_sizes[3] / (3 * B);  // 4096
    const int M   = in_sizes[4] / (3 * B);  // 4096

    const int nb_f1 = B * (Nf / 16);        // 2048
    const int nb_f2 = B * (M  / 16);        // 2048
    const int nb_c1 = B * (Nc / 16);        // 512
    const int r1 = nb_f1;
    const int r2 = r1 + nb_f2;
    const int r3 = r2 + nb_c1;
    const int r4 = r3 + B * (M / 64);       // c2: 64 A-points per block -> 512 blocks
    const int nb = r4 + 1;                  // + kp -> 5121

    hipMemsetAsync(ws, 0, 64, stream);
    fused_all<<<nb, 256, 0, stream>>>(
        pred, target, nkp, coarse, Nc, fine, Nf, gt, M,
        r1, r2, r3, r4,
        1.0f / (B * Nf), 1.0f / (B * M), 1.0f / (B * Nc), 1.0f / (B * M),
        ws, out);
}

// Round 10
// 97.659 us; speedup vs baseline: 2.0503x; 2.0362x over previous
//
#include <hip/hip_runtime.h>
#include <math.h>

// Chamfer with large-chunk LDS staging to maximize compute-per-barrier.
// 256 thr: SLOTS=16 A-slots x NSEG=16 B-segments; 2 A-pts/thread (slot,slot+16)
// -> 32 A-pts/block. B staged in CHUNK-point chunks (CHUNK=2048: 32KB LDS,
// SEG=128 B-pts/thread/chunk = 32 g-iters = ~896 VALU between barriers).
// Segments padded to SEGP=SEG+4: inner-read bank start = (4*sp+4*g)%32,
// 4 sp-groups/wave disjoint -> conflict-free; 16-lane same-addr = broadcast.
// min_b |a-b|^2 = a2 + min_b(b2 - 2 a.b); planes {-2bx,-2by,-2bz,b2}.
#define SBMAX 2112   // NSEG * SEGP at CHUNK=2048: 16*132

template<int CHUNK, bool A_PLANAR, bool B_PLANAR>
__device__ __forceinline__ float chamfer_block(
    const float* __restrict__ A, int An,
    const float* __restrict__ B, int Bn,
    int lbid, float scale,
    float (&sb)[4][SBMAX], float (&red)[512])
{
    constexpr int NSEG    = 16;
    constexpr int SEG     = CHUNK / NSEG;       // 128 (2048) or 64 (1024)
    constexpr int LOG_SEG = (CHUNK == 2048) ? 7 : 6;
    constexpr int SEGP    = SEG + 4;

    const int bpb   = An >> 5;                  // blocks per batch (An/32)
    const int batch = lbid / bpb;
    const int ablk  = lbid % bpb;
    const float* __restrict__ Ab = A + (size_t)batch * 3 * An;
    const float* __restrict__ Bb = B + (size_t)batch * 3 * Bn;

    const int tid  = threadIdx.x;
    const int slot = tid & 15;
    const int sp   = tid >> 4;
    const int p0   = ablk * 32 + slot;
    const int p1   = p0 + 16;

    float a0x, a0y, a0z, a1x, a1y, a1z;
    if (A_PLANAR) {
        a0x = Ab[p0];   a0y = Ab[An + p0];  a0z = Ab[2*An + p0];
        a1x = Ab[p1];   a1y = Ab[An + p1];  a1z = Ab[2*An + p1];
    } else {
        a0x = Ab[3*p0]; a0y = Ab[3*p0 + 1]; a0z = Ab[3*p0 + 2];
        a1x = Ab[3*p1]; a1y = Ab[3*p1 + 1]; a1z = Ab[3*p1 + 2];
    }
    const float a0s = fmaf(a0x, a0x, fmaf(a0y, a0y, a0z * a0z));
    const float a1s = fmaf(a1x, a1x, fmaf(a1y, a1y, a1z * a1z));

    const float BIG = 3.402823466e38f;
    float n00 = BIG, n01 = BIG, n10 = BIG, n11 = BIG;

    for (int t0 = 0; t0 < Bn; t0 += CHUNK) {
        // ---- stage chunk into padded planar layout ----
#pragma unroll
        for (int i = 0; i < CHUNK / 256; ++i) {
            const int k = tid + i * 256;
            float x, y, z;
            if (B_PLANAR) {
                x = Bb[t0 + k]; y = Bb[Bn + t0 + k]; z = Bb[2*Bn + t0 + k];
            } else {
                int base = 3 * (t0 + k);
                x = Bb[base]; y = Bb[base + 1]; z = Bb[base + 2];
            }
            const int addr = (k >> LOG_SEG) * SEGP + (k & (SEG - 1));
            sb[0][addr] = -2.0f * x;
            sb[1][addr] = -2.0f * y;
            sb[2][addr] = -2.0f * z;
            sb[3][addr] = fmaf(x, x, fmaf(y, y, z * z));
        }
        __syncthreads();

        const float4* __restrict__ px = (const float4*)&sb[0][sp * SEGP];
        const float4* __restrict__ py = (const float4*)&sb[1][sp * SEGP];
        const float4* __restrict__ pz = (const float4*)&sb[2][sp * SEGP];
        const float4* __restrict__ pw = (const float4*)&sb[3][sp * SEGP];
#pragma unroll 2
        for (int g = 0; g < SEG / 4; ++g) {
            float4 x = px[g], y = py[g], z = pz[g], w = pw[g];
            float d0, d1, d2, d3;
            d0 = fmaf(a0x, x.x, fmaf(a0y, y.x, fmaf(a0z, z.x, w.x)));
            d1 = fmaf(a0x, x.y, fmaf(a0y, y.y, fmaf(a0z, z.y, w.y)));
            d2 = fmaf(a0x, x.z, fmaf(a0y, y.z, fmaf(a0z, z.z, w.z)));
            d3 = fmaf(a0x, x.w, fmaf(a0y, y.w, fmaf(a0z, z.w, w.w)));
            n00 = fminf(fminf(d0, d1), n00);        // v_min3_f32
            n01 = fminf(fminf(d2, d3), n01);
            d0 = fmaf(a1x, x.x, fmaf(a1y, y.x, fmaf(a1z, z.x, w.x)));
            d1 = fmaf(a1x, x.y, fmaf(a1y, y.y, fmaf(a1z, z.y, w.y)));
            d2 = fmaf(a1x, x.z, fmaf(a1y, y.z, fmaf(a1z, z.z, w.z)));
            d3 = fmaf(a1x, x.w, fmaf(a1y, y.w, fmaf(a1z, z.w, w.w)));
            n10 = fminf(fminf(d0, d1), n10);
            n11 = fminf(fminf(d2, d3), n11);
        }
        __syncthreads();
    }

    // ---- min across the 16 sp-segments, per A-slot ----
    red[sp * 16 + slot]       = fminf(n00, n01);
    red[256 + sp * 16 + slot] = fminf(n10, n11);
    __syncthreads();
#pragma unroll
    for (int st = 8; st > 0; st >>= 1) {
        if (sp < st) {
            red[sp*16 + slot]       = fminf(red[sp*16 + slot],       red[(sp+st)*16 + slot]);
            red[256 + sp*16 + slot] = fminf(red[256 + sp*16 + slot], red[256 + (sp+st)*16 + slot]);
        }
        __syncthreads();
    }

    float contrib = 0.0f;
    if (tid < 16) {
        float d = fmaxf(0.0f, a0s + red[slot]) + fmaxf(0.0f, a1s + red[256 + slot]);
        d *= scale;
#pragma unroll
        for (int off = 8; off > 0; off >>= 1) d += __shfl_down(d, off, 16);
        contrib = d;   // valid at tid 0
    }
    return contrib;
}

__device__ __forceinline__ float kp_block(const float* __restrict__ a,
                                          const float* __restrict__ b, int n,
                                          float (&red)[512])
{
    int tid = threadIdx.x;
    float s = 0.0f;
    for (int i = tid; i < n; i += 256) {
        float d = a[i] - b[i];
        s = fmaf(d, d, s);
    }
    for (int off = 32; off > 0; off >>= 1) s += __shfl_down(s, off, 64);
    if ((tid & 63) == 0) red[tid >> 6] = s;
    __syncthreads();
    float r = 0.0f;
    if (tid == 0) r = (red[0] + red[1] + red[2] + red[3]) / (float)n;
    return r;
}

__global__ __launch_bounds__(256, 4) void fused_all(
    const float* __restrict__ pred, const float* __restrict__ target, int nkp,
    const float* __restrict__ coarse, int Nc,
    const float* __restrict__ fine, int Nf,
    const float* __restrict__ gt, int M,
    int r1, int r2, int r3, int r4,
    float sc_f1, float sc_f2, float sc_c1, float sc_c2,
    float* __restrict__ ws)
{
    __shared__ __align__(16) float sb[4][SBMAX];
    __shared__ float red[512];
    const int bid = blockIdx.x;

    float contrib;
    if (bid < r1)        // fine vs gt: 32 A-pts, 2 chunks of 2048
        contrib = chamfer_block<2048, true,  false>(fine,   Nf, gt,     M,  bid,      sc_f1, sb, red);
    else if (bid < r2)   // gt vs fine: 32 A-pts, 2 chunks of 2048
        contrib = chamfer_block<2048, false, true >(gt,     M,  fine,   Nf, bid - r1, sc_f2, sb, red);
    else if (bid < r3)   // coarse vs gt: 32 A-pts, 2 chunks of 2048
        contrib = chamfer_block<2048, true,  false>(coarse, Nc, gt,     M,  bid - r2, sc_c1, sb, red);
    else if (bid < r4)   // gt vs coarse: 32 A-pts, 1 chunk of 1024
        contrib = chamfer_block<1024, false, true >(gt,     M,  coarse, Nc, bid - r3, sc_c2, sb, red);
    else
        contrib = kp_block(pred, target, nkp, red);

    if (threadIdx.x == 0) ws[bid] = contrib;     // plain store, no atomics
}

__global__ __launch_bounds__(256) void finalize(const float* __restrict__ ws, int n,
                                                float* __restrict__ out)
{
    int tid = threadIdx.x;
    float s = 0.0f;
    for (int i = tid; i < n; i += 256) s += ws[i];
    for (int off = 32; off > 0; off >>= 1) s += __shfl_down(s, off, 64);
    __shared__ float r[4];
    if ((tid & 63) == 0) r[tid >> 6] = s;
    __syncthreads();
    if (tid == 0) out[0] = r[0] + r[1] + r[2] + r[3];
}

extern "C" void kernel_launch(void* const* d_in, const int* in_sizes, int n_in,
                              void* d_out, int out_size, void* d_ws, size_t ws_size,
                              hipStream_t stream) {
    const float* pred   = (const float*)d_in[0];
    const float* target = (const float*)d_in[1];
    const float* coarse = (const float*)d_in[2]; // [B,3,Nc]
    const float* fine   = (const float*)d_in[3]; // [B,3,Nf]
    const float* gt     = (const float*)d_in[4]; // [B,M,3]
    float* out = (float*)d_out;
    float* ws  = (float*)d_ws;

    const int nkp = in_sizes[0];            // 240
    const int B   = nkp / 30;               // 8
    const int Nc  = in_sizes[2] / (3 * B);  // 1024
    const int Nf  = in_sizes[3] / (3 * B);  // 4096
    const int M   = in_sizes[4] / (3 * B);  // 4096

    const int r1 = B * (Nf / 32);           // 1024
    const int r2 = r1 + B * (M / 32);       // +1024
    const int r3 = r2 + B * (Nc / 32);      // +256
    const int r4 = r3 + B * (M / 32);       // +1024
    const int nb = r4 + 1;                  // + kp -> 3330

    fused_all<<<nb, 256, 0, stream>>>(
        pred, target, nkp, coarse, Nc, fine, Nf, gt, M,
        r1, r2, r3, r4,
        1.0f / (B * Nf), 1.0f / (B * M), 1.0f / (B * Nc), 1.0f / (B * M),
        ws);
    finalize<<<1, 256, 0, stream>>>(ws, nb, out);
}